// Round 11
// baseline (156890.674 us; speedup 1.0000x reference)
//
#include <hip/hip_runtime.h>

// ---------------------------------------------------------------------------
// GRUNet, round 11: round-10 kernel UNCHANGED (passing, 25.4ms) + three
// ping-pong diagnostics to measure the store->cross-WG visibility primitive.
// Evidence r1-r10: per-step sync cost ~3.1us invariant under every protocol
// (sc1 broadcast / relay / per-XCD sc1 / per-XCD sc0 publish+poll) while all
// latency models predict 0.2-0.5us. Model is wrong -> measure the primitive.
//   diag_pp_atomic: atomicMax/atomicAdd(p,0) handoffs, N=65536
//   diag_pp_sc1:    plain sc1 store / sc1 load poll,   N=16384
//   diag_pp_sc0:    same-XCD (XCC_ID-verified) sc0,    N=40960
// Bounded spins (cap 16) -> cannot hang. Kernel names appear in the rocprof
// per-dispatch table; dur/N/2 = per-handoff cost. Decision: next round's
// recurrence sync uses the fastest primitive.
// ---------------------------------------------------------------------------

typedef unsigned u32x4 __attribute__((ext_vector_type(4)));
typedef _Float16 h2_t  __attribute__((ext_vector_type(2)));

#define S1 8192
#define S2 256

__device__ u32x4 g_h0s[S1][256];   // records {pair0,pair1,tag,0}
__device__ u32x4 g_h1s[S1][256];
__device__ u32x4 g_q0s[S2][256];
__device__ u32x4 g_q1s[S2][256];
__device__ u32x4 g_loc[4][2][256]; // local (sc0, own-XCD L2) recurrence records
__device__ int   g_claim[128];     // 4 roles x 32 slices
__device__ unsigned g_dflag[48];   // diag flags: [0] atomic, [16] sc1, [32] sc0
__device__ int      g_dclaim[4];   // diag sc0 pair claim

// ---- f16 pack/unpack ----
__device__ __forceinline__ unsigned pk(float a, float b) {
  unsigned short ua = __builtin_bit_cast(unsigned short, (_Float16)a);
  unsigned short ub = __builtin_bit_cast(unsigned short, (_Float16)b);
  return (unsigned)ua | ((unsigned)ub << 16);
}
__device__ __forceinline__ float unpk(unsigned u, int hi) {
  unsigned short us = (unsigned short)(hi ? (u >> 16) : (u & 0xffffu));
  return (float)__builtin_bit_cast(_Float16, us);
}

#if __has_builtin(__builtin_amdgcn_fdot2)
__device__ __forceinline__ float fdot2(unsigned a, unsigned b, float c) {
  return __builtin_amdgcn_fdot2(__builtin_bit_cast(h2_t, a),
                                __builtin_bit_cast(h2_t, b), c, false);
}
#else
__device__ __forceinline__ float fdot2(unsigned a, unsigned b, float c) {
  h2_t ha = __builtin_bit_cast(h2_t, a), hb = __builtin_bit_cast(h2_t, b);
  return c + (float)ha[0] * (float)hb[0] + (float)ha[1] * (float)hb[1];
}
#endif

// ---- scoped loads/stores ----
__device__ __forceinline__ u32x4 ld_sc_v4(const u32x4* p) {   // MALL-coherent
  u32x4 v;
  asm volatile("global_load_dwordx4 %0, %1, off sc1\n\t"
               "s_waitcnt vmcnt(0)" : "=&v"(v) : "v"(p) : "memory");
  return v;
}
__device__ __forceinline__ u32x4 ld_l2_v4(const u32x4* p) {   // own L2
  u32x4 v;
  asm volatile("global_load_dwordx4 %0, %1, off sc0\n\t"
               "s_waitcnt vmcnt(0)" : "=&v"(v) : "v"(p) : "memory");
  return v;
}
__device__ __forceinline__ void st_sc_v4(u32x4* p, u32x4 v) { // -> MALL
  asm volatile("global_store_dwordx4 %0, %1, off sc1" :: "v"(p), "v"(v) : "memory");
}
__device__ __forceinline__ void st_l2_v4(u32x4* p, u32x4 v) { // -> own L2 (dirty)
  asm volatile("global_store_dwordx4 %0, %1, off sc0" :: "v"(p), "v"(v) : "memory");
}
__device__ __forceinline__ unsigned ld_u32_sc1(const unsigned* p) {
  unsigned v;
  asm volatile("global_load_dword %0, %1, off sc1\n\t"
               "s_waitcnt vmcnt(0)" : "=&v"(v) : "v"(p) : "memory");
  return v;
}
__device__ __forceinline__ void st_u32_sc1(unsigned* p, unsigned v) {
  asm volatile("global_store_dword %0, %1, off sc1" :: "v"(p), "v"(v) : "memory");
}
__device__ __forceinline__ unsigned ld_u32_sc0(const unsigned* p) {
  unsigned v;
  asm volatile("global_load_dword %0, %1, off sc0\n\t"
               "s_waitcnt vmcnt(0)" : "=&v"(v) : "v"(p) : "memory");
  return v;
}
__device__ __forceinline__ void st_u32_sc0(unsigned* p, unsigned v) {
  asm volatile("global_store_dword %0, %1, off sc0" :: "v"(p), "v"(v) : "memory");
}

// ---- fast activations ----
__device__ __forceinline__ float rcpf(float x) {
#if __has_builtin(__builtin_amdgcn_rcpf)
  return __builtin_amdgcn_rcpf(x);
#else
  return 1.f / x;
#endif
}
__device__ __forceinline__ float sigf(float x) { return rcpf(1.f + __expf(-x)); }
__device__ __forceinline__ float tanh_f(float x) {
  x = fminf(fmaxf(x, -15.f), 15.f);
  const float e = __expf(2.f * x);
  return (e - 1.f) * rcpf(e + 1.f);
}

// ---- LDS swizzles ----
__device__ __forceinline__ int swzHc(int ch) { return ch ^ ((ch >> 3) & 7); }
__device__ __forceinline__ int swzH_pos(int i) { return (swzHc(i >> 2) << 2) | (i & 3); }
__device__ __forceinline__ int swzX_pos(int i) {
  int ch = i >> 2; ch ^= (ch >> 2) & 7; return (ch << 2) | (i & 3);
}

__global__ void init_all() {
  const long long NH = (long long)S1 * 256;
  const long long NQ = (long long)S2 * 256;
  const long long NL = 4LL * 2 * 256;
  const long long N  = 2 * NH + 2 * NQ + NL;
  u32x4 ff = {0u, 0u, 0xFFFFFFFFu, 0u};
  for (long long k = (long long)blockIdx.x * blockDim.x + threadIdx.x; k < N;
       k += (long long)gridDim.x * blockDim.x) {
    u32x4* r;
    long long k2 = k;
    if (k2 < NH) r = &g_h0s[0][0] + k2;
    else {
      k2 -= NH;
      if (k2 < NH) r = &g_h1s[0][0] + k2;
      else {
        k2 -= NH;
        if (k2 < NQ) r = &g_q0s[0][0] + k2;
        else {
          k2 -= NQ;
          if (k2 < NQ) r = &g_q1s[0][0] + k2;
          else         r = &g_loc[0][0][0] + (k2 - NQ);
        }
      }
    }
    *r = ff;
  }
  if (blockIdx.x == 0) {
    if (threadIdx.x < 128) g_claim[threadIdx.x] = 0;
    if (threadIdx.x < 48)  g_dflag[threadIdx.x] = 0u;
    if (threadIdx.x < 4)   g_dclaim[threadIdx.x] = 0;
  }
}

// ======================= diagnostics: ping-pong RTT =======================
// Monotonic seq handoffs; spin cap 16 -> bounded even if the primitive is
// stale-forever. Per-handoff cost = dispatch_dur / N / 2.
__global__ void diag_pp_atomic() {   // <<<2,64>>>  N=65536
  if (threadIdx.x != 0 || blockIdx.x > 1) return;
  const unsigned me = blockIdx.x;
  for (unsigned k = 0; k < 65536u; ++k) {
    const unsigned tgt = 2u * k + me;
    int c = 0;
    while (atomicAdd(&g_dflag[0], 0u) < tgt && ++c < 16) {}
    atomicMax(&g_dflag[0], tgt + 1u);
  }
}
__global__ void diag_pp_sc1() {      // <<<2,64>>>  N=16384
  if (threadIdx.x != 0 || blockIdx.x > 1) return;
  const unsigned me = blockIdx.x;
  for (unsigned k = 0; k < 16384u; ++k) {
    const unsigned tgt = 2u * k + me;
    int c = 0;
    while (ld_u32_sc1(&g_dflag[16]) < tgt && ++c < 16) {}
    st_u32_sc1(&g_dflag[16], tgt + 1u);
  }
}
__global__ void diag_pp_sc0() {      // <<<64,64>>> N=40960, pair XCC-verified
  __shared__ int sRole;
  if (threadIdx.x == 0) {
    unsigned xcc;
    asm volatile("s_getreg_b32 %0, hwreg(HW_REG_XCC_ID)" : "=s"(xcc));
    xcc &= 7u;
    int role = -1;
    if (xcc == 0u) { int i = atomicAdd(&g_dclaim[0], 1); if (i < 2) role = i; }
    sRole = role;
  }
  __syncthreads();
  const int me = sRole;
  if (me < 0 || threadIdx.x != 0) return;
  for (unsigned k = 0; k < 40960u; ++k) {
    const unsigned tgt = 2u * k + (unsigned)me;
    int c = 0;
    while (ld_u32_sc0(&g_dflag[32]) < tgt && ++c < 16) {}
    st_u32_sc0(&g_dflag[32], tgt + 1u);
  }
}

__device__ __forceinline__ const u32x4* in_addr(int role, int u, int r) {
  if (role == 1) return &g_h0s[u][r];
  if (role == 2) {
    const int ss = ((u >> 1) << 6) + 63;
    return (u & 1) ? &g_h1s[ss][r] : &g_h0s[ss][r];
  }
  return &g_q0s[u][r];
}
__device__ __forceinline__ unsigned in_want(int role, int u) {
  return (role == 2) ? (unsigned)(((u >> 1) << 6) + 63) : (unsigned)u;
}

#define MAC4(A, W4, H4)                                                       \
  A = fdot2((W4)[0], (H4)[0], A); A = fdot2((W4)[1], (H4)[1], A);             \
  A = fdot2((W4)[2], (H4)[2], A); A = fdot2((W4)[3], (H4)[3], A);

#define RED16(A)                                                              \
  A += __shfl_xor(A, 8, 16); A += __shfl_xor(A, 4, 16);                       \
  A += __shfl_xor(A, 2, 16); A += __shfl_xor(A, 1, 16);

__global__
__attribute__((amdgpu_flat_work_group_size(512, 512), amdgpu_waves_per_eu(2, 2)))
void gru_all(const float* __restrict__ x,
             const float* __restrict__ g1_Wi0, const float* __restrict__ g1_Wh0,
             const float* __restrict__ g1_bi0, const float* __restrict__ g1_bh0,
             const float* __restrict__ g1_Wi1, const float* __restrict__ g1_Wh1,
             const float* __restrict__ g1_bi1, const float* __restrict__ g1_bh1,
             const float* __restrict__ g2_Wi0, const float* __restrict__ g2_Wh0,
             const float* __restrict__ g2_bi0, const float* __restrict__ g2_bh0,
             const float* __restrict__ g2_Wi1, const float* __restrict__ g2_Wh1,
             const float* __restrict__ g2_bi1, const float* __restrict__ g2_bh1,
             const float* __restrict__ fc1W, const float* __restrict__ fc1b,
             const float* __restrict__ fc2W, const float* __restrict__ fc2b,
             float* __restrict__ out)
{
  const int tid = threadIdx.x;
  const int G   = tid >> 4;            // 32 groups of 16 lanes
  const int q   = tid & 15;
  const int rid = tid - 256;           // stream-thread id (valid for tid>=256)

  __shared__ __attribute__((aligned(16))) unsigned sH[2][512];   // own h[s-1]
  __shared__ __attribute__((aligned(16))) unsigned sIN[8][512];  // stream ring
  __shared__ __attribute__((aligned(16))) unsigned sX[8][256];   // x ring (role0)
  __shared__ float sD[96];             // Wh row dots (rr = gate*32+elem)
  __shared__ float sDI[96];            // Wi row dots
  __shared__ float sY[128];
  __shared__ int   sSlot;

  unsigned xcc;
  asm volatile("s_getreg_b32 %0, hwreg(HW_REG_XCC_ID)" : "=s"(xcc));
  xcc &= 7u;
  if (tid == 0) {
    int slot = -1;
    if (xcc < 4u) {
      for (int i = 0; i < 32 && slot < 0; ++i)
        if (atomicCAS(&g_claim[(int)xcc * 32 + i], 0, 1) == 0)
          slot = (int)xcc * 32 + i;
    }
    if (slot < 0) {
      for (int k = 0; k < 32; ++k) __builtin_amdgcn_s_sleep(64);  // ~60us
      for (int i = 0; i < 128 && slot < 0; ++i)
        if (atomicCAS(&g_claim[i], 0, 1) == 0) slot = i;
    }
    sSlot = slot;
  }
  __syncthreads();
  const int slot = sSlot;
  if (slot < 0) return;                // surplus WG
  const int role = slot >> 5;          // 0..3
  const int rank = slot & 31;          // h-slice [32*rank, +32)
  const int e0   = rank * 32;
  const bool lp  = ((int)xcc == role);
  const int S    = (role <= 1) ? S1 : S2;

  const float* Wh  = (role == 0) ? g1_Wh0 : (role == 1) ? g1_Wh1
                   : (role == 2) ? g2_Wh0 : g2_Wh1;
  const float* Wi  = (role == 0) ? g1_Wi0 : (role == 1) ? g1_Wi1
                   : (role == 2) ? g2_Wi0 : g2_Wi1;
  const float* pbi = (role == 0) ? g1_bi0 : (role == 1) ? g1_bi1
                   : (role == 2) ? g2_bi0 : g2_bi1;
  const float* pbh = (role == 0) ? g1_bh0 : (role == 1) ? g1_bh1
                   : (role == 2) ? g2_bh0 : g2_bh1;
  u32x4 (*outA)[256] = (role == 0) ? g_h0s : (role == 1) ? g_h1s
                     : (role == 2) ? g_q0s : g_q1s;

  u32x4 wv[6][8];
  {
    const bool isWh = (G < 16);
    const int  Gm   = isWh ? G : (G - 16);
    const float* M  = isWh ? Wh : Wi;
    const bool wide = isWh || (role != 0);
    #pragma unroll
    for (int j = 0; j < 6; ++j) {
      const int rr = Gm * 6 + j;
      const int R  = (rr >> 5) * 1024 + e0 + (rr & 31);
      if (wide) {
        const float4* rp = (const float4*)(M + (size_t)R * 1024 + 64 * q);
        #pragma unroll
        for (int c = 0; c < 8; ++c) {
          float4 a = rp[2 * c], b = rp[2 * c + 1];
          wv[j][c] = (u32x4){pk(a.x, a.y), pk(a.z, a.w), pk(b.x, b.y), pk(b.z, b.w)};
        }
      } else {
        const float4* rp = (const float4*)(M + (size_t)R * 512 + 32 * q);
        #pragma unroll
        for (int c = 0; c < 4; ++c) {
          float4 a = rp[2 * c], b = rp[2 * c + 1];
          wv[j][c] = (u32x4){pk(a.x, a.y), pk(a.z, a.w), pk(b.x, b.y), pk(b.z, b.w)};
        }
      }
    }
  }

  float bIr = 0, bIz = 0, bIn = 0, bHr = 0, bHz = 0, bHn = 0;
  if (tid < 32) {
    const int ge = e0 + tid;
    bIr = pbi[ge]; bIz = pbi[1024 + ge]; bIn = pbi[2048 + ge];
    bHr = pbh[ge]; bHz = pbh[1024 + ge]; bHn = pbh[2048 + ge];
  }

  if (tid >= 256) {
    if (role == 0) {
      #pragma unroll
      for (int u = 0; u < 4; ++u) {
        float2 xv = ((const float2*)(x + (size_t)((u & 63) * 128 + (u >> 6)) * 512))[rid];
        sX[u][swzX_pos(rid)] = pk(xv.x, xv.y);
      }
    } else {
      for (int u = 0; u < 4; ++u) {
        const u32x4* a = in_addr(role, u, rid);
        const unsigned w = in_want(role, u);
        u32x4 r = ld_sc_v4(a);
        while (r[2] != w) r = ld_sc_v4(a);
        sIN[u][swzH_pos(2 * rid)]     = r[0];
        sIN[u][swzH_pos(2 * rid + 1)] = r[1];
      }
    }
  }
  __syncthreads();

  for (int s = 0; s < S; ++s) {
    const int par = s & 1;

    if (tid >= 256 && (s & 3) == 0) {
      if (role == 0) {
        #pragma unroll
        for (int k = 0; k < 4; ++k) {
          const int u = s + 4 + k;
          if (u < S) {
            float2 xv = ((const float2*)(x + (size_t)((u & 63) * 128 + (u >> 6)) * 512))[rid];
            sX[u & 7][swzX_pos(rid)] = pk(xv.x, xv.y);
          }
        }
      } else {
        #pragma unroll
        for (int k = 0; k < 4; ++k) {
          const int u = s + 4 + k;
          if (u < S) {
            const u32x4* a = in_addr(role, u, rid);
            const unsigned w = in_want(role, u);
            u32x4 r = ld_sc_v4(a);
            while (r[2] != w) r = ld_sc_v4(a);
            sIN[u & 7][swzH_pos(2 * rid)]     = r[0];
            sIN[u & 7][swzH_pos(2 * rid + 1)] = r[1];
          }
        }
      }
    }

    if (tid < 256) {
      unsigned d0 = 0, d1 = 0;
      if (s > 0) {
        const unsigned w = (unsigned)(s - 1);
        const u32x4* ga = &outA[s - 1][tid];
        u32x4 r;
        if (lp) {
          const u32x4* la = &g_loc[role][(s - 1) & 1][tid];
          r = ld_l2_v4(la);
          int spin = 0;
          while (r[2] != w)
            r = (((++spin) & 7) == 0) ? ld_sc_v4(ga) : ld_l2_v4(la);
        } else {
          r = ld_sc_v4(ga);
          while (r[2] != w) r = ld_sc_v4(ga);
        }
        d0 = r[0]; d1 = r[1];
      }
      sH[par][swzH_pos(2 * tid)]     = d0;
      sH[par][swzH_pos(2 * tid + 1)] = d1;
    }
    __syncthreads();                                   // barrier 1

    float a0 = 0, a1 = 0, a2 = 0, a3 = 0, a4 = 0, a5 = 0;
    if (G < 16) {
      const u32x4* HV = (const u32x4*)sH[par];
      #pragma unroll
      for (int c = 0; c < 8; ++c) {
        const u32x4 h4 = HV[8 * q + (c ^ (q & 7))];
        MAC4(a0, wv[0][c], h4); MAC4(a1, wv[1][c], h4); MAC4(a2, wv[2][c], h4);
        MAC4(a3, wv[3][c], h4); MAC4(a4, wv[4][c], h4); MAC4(a5, wv[5][c], h4);
      }
    } else if (role != 0) {
      const u32x4* IV = (const u32x4*)sIN[s & 7];
      #pragma unroll
      for (int c = 0; c < 8; ++c) {
        const u32x4 h4 = IV[8 * q + (c ^ (q & 7))];
        MAC4(a0, wv[0][c], h4); MAC4(a1, wv[1][c], h4); MAC4(a2, wv[2][c], h4);
        MAC4(a3, wv[3][c], h4); MAC4(a4, wv[4][c], h4); MAC4(a5, wv[5][c], h4);
      }
    } else {
      const u32x4* XV = (const u32x4*)sX[s & 7];
      #pragma unroll
      for (int c = 0; c < 4; ++c) {
        const int ch = 4 * q + c;
        const u32x4 h4 = XV[ch ^ ((ch >> 2) & 7)];
        MAC4(a0, wv[0][c], h4); MAC4(a1, wv[1][c], h4); MAC4(a2, wv[2][c], h4);
        MAC4(a3, wv[3][c], h4); MAC4(a4, wv[4][c], h4); MAC4(a5, wv[5][c], h4);
      }
    }
    RED16(a0); RED16(a1); RED16(a2); RED16(a3); RED16(a4); RED16(a5);
    if (q < 6) {
      const float v = (q == 0) ? a0 : (q == 1) ? a1 : (q == 2) ? a2
                    : (q == 3) ? a3 : (q == 4) ? a4 : a5;
      if (G < 16) sD[G * 6 + q] = v;
      else        sDI[(G - 16) * 6 + q] = v;
    }
    __syncthreads();                                   // barrier 2

    if (tid < 32) {
      const float rg = sigf(sDI[tid] + bIr + sD[tid] + bHr);
      const float zg = sigf(sDI[32 + tid] + bIz + sD[32 + tid] + bHz);
      const float ng = tanh_f(sDI[64 + tid] + bIn + rg * (sD[64 + tid] + bHn));
      const int ge = e0 + tid;
      const float hp = unpk(sH[par][swzH_pos(ge >> 1)], ge & 1);
      const float hn = (1.f - zg) * ng + zg * hp;
      const int b4 = (tid & 7) * 4;
      const float v0 = __shfl(hn, b4),     v1 = __shfl(hn, b4 + 1);
      const float v2 = __shfl(hn, b4 + 2), v3 = __shfl(hn, b4 + 3);
      if (tid < 8) {
        u32x4 rec = {pk(v0, v1), pk(v2, v3), (unsigned)s, 0u};
        if (lp) st_l2_v4(&g_loc[role][s & 1][rank * 8 + tid], rec);
        st_sc_v4(&outA[s][rank * 8 + tid], rec);
      }
    }
  }

  if (role == 3 && rank == 0) {
    if (tid < 256) {
      const u32x4* a = &g_q0s[S2 - 1][tid];
      u32x4 r = ld_sc_v4(a);
      while (r[2] != (unsigned)(S2 - 1)) r = ld_sc_v4(a);
      sH[0][swzH_pos(2 * tid)]     = r[0];
      sH[0][swzH_pos(2 * tid + 1)] = r[1];
    } else {
      const u32x4* a = &g_q1s[S2 - 1][rid];
      u32x4 r = ld_sc_v4(a);
      while (r[2] != (unsigned)(S2 - 1)) r = ld_sc_v4(a);
      sH[1][swzH_pos(2 * rid)]     = r[0];
      sH[1][swzH_pos(2 * rid + 1)] = r[1];
    }
    __syncthreads();
    if (tid < 128) {
      const int l = tid >> 6, k = tid & 63;
      const unsigned* Hs = (const unsigned*)sH[l];
      const float* wrow = fc1W + (size_t)k * 1024;
      float acc = fc1b[k];
      for (int j2 = 0; j2 < 512; ++j2) {
        const unsigned hu = Hs[swzH_pos(j2)];
        acc += unpk(hu, 0) * wrow[2 * j2] + unpk(hu, 1) * wrow[2 * j2 + 1];
      }
      sY[tid] = sigf(acc);
    }
    __syncthreads();
    if (tid < 2) {
      const float* yv = sY + tid * 64;
      float acc = fc2b[0];
      for (int k2 = 0; k2 < 64; ++k2) acc += fc2W[k2] * yv[k2];
      out[tid] = sigf(acc);
    }
  }
}

extern "C" void kernel_launch(void* const* d_in, const int* in_sizes, int n_in,
                              void* d_out, int out_size, void* d_ws, size_t ws_size,
                              hipStream_t stream) {
  (void)in_sizes; (void)n_in; (void)out_size; (void)d_ws; (void)ws_size;
  const float* x      = (const float*)d_in[0];
  const float* g1_Wi0 = (const float*)d_in[1];
  const float* g1_Wh0 = (const float*)d_in[2];
  const float* g1_bi0 = (const float*)d_in[3];
  const float* g1_bh0 = (const float*)d_in[4];
  const float* g1_Wi1 = (const float*)d_in[5];
  const float* g1_Wh1 = (const float*)d_in[6];
  const float* g1_bi1 = (const float*)d_in[7];
  const float* g1_bh1 = (const float*)d_in[8];
  const float* g2_Wi0 = (const float*)d_in[9];
  const float* g2_Wh0 = (const float*)d_in[10];
  const float* g2_bi0 = (const float*)d_in[11];
  const float* g2_bh0 = (const float*)d_in[12];
  const float* g2_Wi1 = (const float*)d_in[13];
  const float* g2_Wh1 = (const float*)d_in[14];
  const float* g2_bi1 = (const float*)d_in[15];
  const float* g2_bh1 = (const float*)d_in[16];
  const float* fc1W   = (const float*)d_in[17];
  const float* fc1b   = (const float*)d_in[18];
  const float* fc2W   = (const float*)d_in[19];
  const float* fc2b   = (const float*)d_in[20];
  float* out = (float*)d_out;

  init_all<<<dim3(2048), dim3(256), 0, stream>>>();
  diag_pp_atomic<<<dim3(2), dim3(64), 0, stream>>>();
  diag_pp_sc1<<<dim3(2), dim3(64), 0, stream>>>();
  diag_pp_sc0<<<dim3(64), dim3(64), 0, stream>>>();
  gru_all<<<dim3(256), dim3(512), 0, stream>>>(
      x, g1_Wi0, g1_Wh0, g1_bi0, g1_bh0, g1_Wi1, g1_Wh1, g1_bi1, g1_bh1,
      g2_Wi0, g2_Wh0, g2_bi0, g2_bh0, g2_Wi1, g2_Wh1, g2_bi1, g2_bh1,
      fc1W, fc1b, fc2W, fc2b, out);
}

// Round 12
// 25437.822 us; speedup vs baseline: 6.1676x; 6.1676x over previous
//
#include <hip/hip_runtime.h>

// ---------------------------------------------------------------------------
// GRUNet, round 12: round-10 architecture + atomic64 recurrence records.
// r11 primitive measurements (ping-pong):
//   atomic cross-XCD handoff ~0.72us  |  sc1 load-poll RTT ~1.5us  |
//   sc0 cross-WG visibility: NEVER (spins to cap) -- sc0 path deleted.
// Lever: recurrence record = one 64b atomic {seq:32 | 2xf16:32} in
// g_fast[role][parity][512]. Publish: 16 atomicExch per WG (data+tag one op,
// HW-coherent). Poll: tid<256 each atomicAdd(p,0) on its 2 records.
// No overwrite hazard: slot [s&1] is re-written at s only after all WGs
// polled s-1, which requires all polls of s-2 complete. Re-init per launch.
// sc1 stores kept for history/streams (latency-tolerant, off critical path).
//   role r on XCD r: 32 WGs x 512 thr; roles: 0=gru1.l0(x) 1=gru1.l1(h0s)
//   2=gru2.l0(samples) 3=gru2.l1(q0s)+FC tail.
// ---------------------------------------------------------------------------

typedef unsigned u32x4 __attribute__((ext_vector_type(4)));
typedef _Float16 h2_t  __attribute__((ext_vector_type(2)));

#define S1 8192
#define S2 256

__device__ u32x4 g_h0s[S1][256];   // history records {pair0,pair1,tag,0} (sc1)
__device__ u32x4 g_h1s[S1][256];
__device__ u32x4 g_q0s[S2][256];
__device__ u32x4 g_q1s[S2][256];
__device__ unsigned long long g_fast[4][2][512];  // {seq:32 | 2xf16:32}
__device__ int   g_claim[128];     // 4 roles x 32 slices

// ---- f16 pack/unpack ----
__device__ __forceinline__ unsigned pk(float a, float b) {
  unsigned short ua = __builtin_bit_cast(unsigned short, (_Float16)a);
  unsigned short ub = __builtin_bit_cast(unsigned short, (_Float16)b);
  return (unsigned)ua | ((unsigned)ub << 16);
}
__device__ __forceinline__ float unpk(unsigned u, int hi) {
  unsigned short us = (unsigned short)(hi ? (u >> 16) : (u & 0xffffu));
  return (float)__builtin_bit_cast(_Float16, us);
}

#if __has_builtin(__builtin_amdgcn_fdot2)
__device__ __forceinline__ float fdot2(unsigned a, unsigned b, float c) {
  return __builtin_amdgcn_fdot2(__builtin_bit_cast(h2_t, a),
                                __builtin_bit_cast(h2_t, b), c, false);
}
#else
__device__ __forceinline__ float fdot2(unsigned a, unsigned b, float c) {
  h2_t ha = __builtin_bit_cast(h2_t, a), hb = __builtin_bit_cast(h2_t, b);
  return c + (float)ha[0] * (float)hb[0] + (float)ha[1] * (float)hb[1];
}
#endif

// ---- sc1 (MALL-coherent) 16B load/store for streams/history ----
__device__ __forceinline__ u32x4 ld_sc_v4(const u32x4* p) {
  u32x4 v;
  asm volatile("global_load_dwordx4 %0, %1, off sc1\n\t"
               "s_waitcnt vmcnt(0)" : "=&v"(v) : "v"(p) : "memory");
  return v;
}
__device__ __forceinline__ void st_sc_v4(u32x4* p, u32x4 v) {
  asm volatile("global_store_dwordx4 %0, %1, off sc1" :: "v"(p), "v"(v) : "memory");
}

// ---- fast activations ----
__device__ __forceinline__ float rcpf(float x) {
#if __has_builtin(__builtin_amdgcn_rcpf)
  return __builtin_amdgcn_rcpf(x);
#else
  return 1.f / x;
#endif
}
__device__ __forceinline__ float sigf(float x) { return rcpf(1.f + __expf(-x)); }
__device__ __forceinline__ float tanh_f(float x) {
  x = fminf(fmaxf(x, -15.f), 15.f);
  const float e = __expf(2.f * x);
  return (e - 1.f) * rcpf(e + 1.f);
}

// ---- LDS swizzles ----
__device__ __forceinline__ int swzHc(int ch) { return ch ^ ((ch >> 3) & 7); }
__device__ __forceinline__ int swzH_pos(int i) { return (swzHc(i >> 2) << 2) | (i & 3); }
__device__ __forceinline__ int swzX_pos(int i) {
  int ch = i >> 2; ch ^= (ch >> 2) & 7; return (ch << 2) | (i & 3);
}

__global__ void init_all() {
  const long long NH = (long long)S1 * 256;
  const long long NQ = (long long)S2 * 256;
  const long long N  = 2 * NH + 2 * NQ;
  u32x4 ff = {0u, 0u, 0xFFFFFFFFu, 0u};
  const long long idx = (long long)blockIdx.x * blockDim.x + threadIdx.x;
  const long long str = (long long)gridDim.x * blockDim.x;
  for (long long k = idx; k < N; k += str) {
    u32x4* r;
    long long k2 = k;
    if (k2 < NH) r = &g_h0s[0][0] + k2;
    else {
      k2 -= NH;
      if (k2 < NH) r = &g_h1s[0][0] + k2;
      else {
        k2 -= NH;
        if (k2 < NQ) r = &g_q0s[0][0] + k2;
        else         r = &g_q1s[0][0] + (k2 - NQ);
      }
    }
    *r = ff;
  }
  for (long long k = idx; k < 4LL * 2 * 512; k += str)
    ((unsigned long long*)g_fast)[k] = 0xFFFFFFFF00000000ULL;
  if (blockIdx.x == 0 && threadIdx.x < 128) g_claim[threadIdx.x] = 0;
}

__device__ __forceinline__ const u32x4* in_addr(int role, int u, int r) {
  if (role == 1) return &g_h0s[u][r];
  if (role == 2) {
    const int ss = ((u >> 1) << 6) + 63;
    return (u & 1) ? &g_h1s[ss][r] : &g_h0s[ss][r];
  }
  return &g_q0s[u][r];
}
__device__ __forceinline__ unsigned in_want(int role, int u) {
  return (role == 2) ? (unsigned)(((u >> 1) << 6) + 63) : (unsigned)u;
}

#define MAC4(A, W4, H4)                                                       \
  A = fdot2((W4)[0], (H4)[0], A); A = fdot2((W4)[1], (H4)[1], A);             \
  A = fdot2((W4)[2], (H4)[2], A); A = fdot2((W4)[3], (H4)[3], A);

#define RED16(A)                                                              \
  A += __shfl_xor(A, 8, 16); A += __shfl_xor(A, 4, 16);                       \
  A += __shfl_xor(A, 2, 16); A += __shfl_xor(A, 1, 16);

__global__
__attribute__((amdgpu_flat_work_group_size(512, 512), amdgpu_waves_per_eu(2, 2)))
void gru_all(const float* __restrict__ x,
             const float* __restrict__ g1_Wi0, const float* __restrict__ g1_Wh0,
             const float* __restrict__ g1_bi0, const float* __restrict__ g1_bh0,
             const float* __restrict__ g1_Wi1, const float* __restrict__ g1_Wh1,
             const float* __restrict__ g1_bi1, const float* __restrict__ g1_bh1,
             const float* __restrict__ g2_Wi0, const float* __restrict__ g2_Wh0,
             const float* __restrict__ g2_bi0, const float* __restrict__ g2_bh0,
             const float* __restrict__ g2_Wi1, const float* __restrict__ g2_Wh1,
             const float* __restrict__ g2_bi1, const float* __restrict__ g2_bh1,
             const float* __restrict__ fc1W, const float* __restrict__ fc1b,
             const float* __restrict__ fc2W, const float* __restrict__ fc2b,
             float* __restrict__ out)
{
  const int tid = threadIdx.x;
  const int G   = tid >> 4;            // 32 groups of 16 lanes
  const int q   = tid & 15;
  const int rid = tid - 256;           // stream-thread id (valid for tid>=256)

  __shared__ __attribute__((aligned(16))) unsigned sH[2][512];   // own h[s-1]
  __shared__ __attribute__((aligned(16))) unsigned sIN[8][512];  // stream ring
  __shared__ __attribute__((aligned(16))) unsigned sX[8][256];   // x ring (role0)
  __shared__ float sD[96];             // Wh row dots
  __shared__ float sDI[96];            // Wi row dots
  __shared__ float sY[128];
  __shared__ int   sSlot;

  // ---- slot claim: prefer own-XCD role; bounded global fallback ----
  unsigned xcc;
  asm volatile("s_getreg_b32 %0, hwreg(HW_REG_XCC_ID)" : "=s"(xcc));
  xcc &= 7u;
  if (tid == 0) {
    int slot = -1;
    if (xcc < 4u) {
      for (int i = 0; i < 32 && slot < 0; ++i)
        if (atomicCAS(&g_claim[(int)xcc * 32 + i], 0, 1) == 0)
          slot = (int)xcc * 32 + i;
    }
    if (slot < 0) {
      for (int k = 0; k < 32; ++k) __builtin_amdgcn_s_sleep(64);  // ~60us
      for (int i = 0; i < 128 && slot < 0; ++i)
        if (atomicCAS(&g_claim[i], 0, 1) == 0) slot = i;
    }
    sSlot = slot;
  }
  __syncthreads();
  const int slot = sSlot;
  if (slot < 0) return;                // surplus WG
  const int role = slot >> 5;          // 0..3
  const int rank = slot & 31;          // h-slice [32*rank, +32)
  const int e0   = rank * 32;
  const int S    = (role <= 1) ? S1 : S2;

  const float* Wh  = (role == 0) ? g1_Wh0 : (role == 1) ? g1_Wh1
                   : (role == 2) ? g2_Wh0 : g2_Wh1;
  const float* Wi  = (role == 0) ? g1_Wi0 : (role == 1) ? g1_Wi1
                   : (role == 2) ? g2_Wi0 : g2_Wi1;
  const float* pbi = (role == 0) ? g1_bi0 : (role == 1) ? g1_bi1
                   : (role == 2) ? g2_bi0 : g2_bi1;
  const float* pbh = (role == 0) ? g1_bh0 : (role == 1) ? g1_bh1
                   : (role == 2) ? g2_bh0 : g2_bh1;
  u32x4 (*outA)[256] = (role == 0) ? g_h0s : (role == 1) ? g_h1s
                     : (role == 2) ? g_q0s : g_q1s;

  // ---- weights -> registers: group (G) owns 6 rows of ONE matrix ----
  u32x4 wv[6][8];
  {
    const bool isWh = (G < 16);
    const int  Gm   = isWh ? G : (G - 16);
    const float* M  = isWh ? Wh : Wi;
    const bool wide = isWh || (role != 0);
    #pragma unroll
    for (int j = 0; j < 6; ++j) {
      const int rr = Gm * 6 + j;
      const int R  = (rr >> 5) * 1024 + e0 + (rr & 31);
      if (wide) {
        const float4* rp = (const float4*)(M + (size_t)R * 1024 + 64 * q);
        #pragma unroll
        for (int c = 0; c < 8; ++c) {
          float4 a = rp[2 * c], b = rp[2 * c + 1];
          wv[j][c] = (u32x4){pk(a.x, a.y), pk(a.z, a.w), pk(b.x, b.y), pk(b.z, b.w)};
        }
      } else {
        const float4* rp = (const float4*)(M + (size_t)R * 512 + 32 * q);
        #pragma unroll
        for (int c = 0; c < 4; ++c) {
          float4 a = rp[2 * c], b = rp[2 * c + 1];
          wv[j][c] = (u32x4){pk(a.x, a.y), pk(a.z, a.w), pk(b.x, b.y), pk(b.z, b.w)};
        }
      }
    }
  }

  // ---- biases for combine lanes (tid<32 -> elem e0+tid) ----
  float bIr = 0, bIz = 0, bIn = 0, bHr = 0, bHz = 0, bHn = 0;
  if (tid < 32) {
    const int ge = e0 + tid;
    bIr = pbi[ge]; bIz = pbi[1024 + ge]; bIn = pbi[2048 + ge];
    bHr = pbh[ge]; bHz = pbh[1024 + ge]; bHn = pbh[2048 + ge];
  }

  // ---- stream prologue: fill ring slots 0..3 ----
  if (tid >= 256) {
    if (role == 0) {
      #pragma unroll
      for (int u = 0; u < 4; ++u) {
        float2 xv = ((const float2*)(x + (size_t)((u & 63) * 128 + (u >> 6)) * 512))[rid];
        sX[u][swzX_pos(rid)] = pk(xv.x, xv.y);
      }
    } else {
      for (int u = 0; u < 4; ++u) {
        const u32x4* a = in_addr(role, u, rid);
        const unsigned w = in_want(role, u);
        u32x4 r = ld_sc_v4(a);
        while (r[2] != w) r = ld_sc_v4(a);
        sIN[u][swzH_pos(2 * rid)]     = r[0];
        sIN[u][swzH_pos(2 * rid + 1)] = r[1];
      }
    }
  }
  __syncthreads();

  // =======================  serial scan  =======================
  for (int s = 0; s < S; ++s) {
    const int par = s & 1;

    // ---- stream batch-fetch: every 4th iter, steps s+4..s+7 (tid>=256) ----
    if (tid >= 256 && (s & 3) == 0) {
      if (role == 0) {
        #pragma unroll
        for (int k = 0; k < 4; ++k) {
          const int u = s + 4 + k;
          if (u < S) {
            float2 xv = ((const float2*)(x + (size_t)((u & 63) * 128 + (u >> 6)) * 512))[rid];
            sX[u & 7][swzX_pos(rid)] = pk(xv.x, xv.y);
          }
        }
      } else {
        #pragma unroll
        for (int k = 0; k < 4; ++k) {
          const int u = s + 4 + k;
          if (u < S) {
            const u32x4* a = in_addr(role, u, rid);
            const unsigned w = in_want(role, u);
            u32x4 r = ld_sc_v4(a);
            while (r[2] != w) r = ld_sc_v4(a);
            sIN[u & 7][swzH_pos(2 * rid)]     = r[0];
            sIN[u & 7][swzH_pos(2 * rid + 1)] = r[1];
          }
        }
      }
    }

    // ---- own recurrence poll: atomic64 records (data+seq in one op) ----
    if (tid < 256) {
      unsigned d0 = 0, d1 = 0;
      if (s > 0) {
        const unsigned w = (unsigned)(s - 1);
        unsigned long long* f0 = &g_fast[role][(s - 1) & 1][2 * tid];
        unsigned long long* f1 = f0 + 1;
        unsigned long long v0 = atomicAdd(f0, 0ull);
        unsigned long long v1 = atomicAdd(f1, 0ull);
        bool o0 = ((unsigned)(v0 >> 32) == w), o1 = ((unsigned)(v1 >> 32) == w);
        while (!(o0 && o1)) {
          if (!o0) v0 = atomicAdd(f0, 0ull);
          if (!o1) v1 = atomicAdd(f1, 0ull);
          o0 = ((unsigned)(v0 >> 32) == w); o1 = ((unsigned)(v1 >> 32) == w);
        }
        d0 = (unsigned)v0; d1 = (unsigned)v1;
      }
      sH[par][swzH_pos(2 * tid)]     = d0;
      sH[par][swzH_pos(2 * tid + 1)] = d1;
    }
    __syncthreads();                                   // barrier 1

    // ---- row dots (register weights x LDS operand) ----
    float a0 = 0, a1 = 0, a2 = 0, a3 = 0, a4 = 0, a5 = 0;
    if (G < 16) {                                      // Wh groups: h[s-1]
      const u32x4* HV = (const u32x4*)sH[par];
      #pragma unroll
      for (int c = 0; c < 8; ++c) {
        const u32x4 h4 = HV[8 * q + (c ^ (q & 7))];
        MAC4(a0, wv[0][c], h4); MAC4(a1, wv[1][c], h4); MAC4(a2, wv[2][c], h4);
        MAC4(a3, wv[3][c], h4); MAC4(a4, wv[4][c], h4); MAC4(a5, wv[5][c], h4);
      }
    } else if (role != 0) {                            // Wi groups: stream
      const u32x4* IV = (const u32x4*)sIN[s & 7];
      #pragma unroll
      for (int c = 0; c < 8; ++c) {
        const u32x4 h4 = IV[8 * q + (c ^ (q & 7))];
        MAC4(a0, wv[0][c], h4); MAC4(a1, wv[1][c], h4); MAC4(a2, wv[2][c], h4);
        MAC4(a3, wv[3][c], h4); MAC4(a4, wv[4][c], h4); MAC4(a5, wv[5][c], h4);
      }
    } else {                                           // role0 Wi: x (512 col)
      const u32x4* XV = (const u32x4*)sX[s & 7];
      #pragma unroll
      for (int c = 0; c < 4; ++c) {
        const int ch = 4 * q + c;
        const u32x4 h4 = XV[ch ^ ((ch >> 2) & 7)];
        MAC4(a0, wv[0][c], h4); MAC4(a1, wv[1][c], h4); MAC4(a2, wv[2][c], h4);
        MAC4(a3, wv[3][c], h4); MAC4(a4, wv[4][c], h4); MAC4(a5, wv[5][c], h4);
      }
    }
    RED16(a0); RED16(a1); RED16(a2); RED16(a3); RED16(a4); RED16(a5);
    if (q < 6) {
      const float v = (q == 0) ? a0 : (q == 1) ? a1 : (q == 2) ? a2
                    : (q == 3) ? a3 : (q == 4) ? a4 : a5;
      if (G < 16) sD[G * 6 + q] = v;
      else        sDI[(G - 16) * 6 + q] = v;
    }
    __syncthreads();                                   // barrier 2

    // ---- gate combine + publish (lanes 0..31 of wave 0) ----
    if (tid < 32) {
      const float rg = sigf(sDI[tid] + bIr + sD[tid] + bHr);
      const float zg = sigf(sDI[32 + tid] + bIz + sD[32 + tid] + bHz);
      const float ng = tanh_f(sDI[64 + tid] + bIn + rg * (sD[64 + tid] + bHn));
      const int ge = e0 + tid;
      const float hp = unpk(sH[par][swzH_pos(ge >> 1)], ge & 1);
      const float hn = (1.f - zg) * ng + zg * hp;
      // shuffles with all 32 source lanes active (r8-proven); stores guarded.
      const int i2 = (tid & 15) * 2;
      const float p0 = __shfl(hn, i2), p1 = __shfl(hn, i2 + 1);
      const int b4 = (tid & 7) * 4;
      const float v0 = __shfl(hn, b4),     v1 = __shfl(hn, b4 + 1);
      const float v2 = __shfl(hn, b4 + 2), v3 = __shfl(hn, b4 + 3);
      if (tid < 16) {                                  // fast path FIRST
        unsigned long long val =
            ((unsigned long long)(unsigned)s << 32) | (unsigned long long)pk(p0, p1);
        atomicExch(&g_fast[role][s & 1][rank * 16 + tid], val);
      }
      if (tid < 8) {                                   // history/stream (sc1)
        u32x4 rec = {pk(v0, v1), pk(v2, v3), (unsigned)s, 0u};
        st_sc_v4(&outA[s][rank * 8 + tid], rec);
      }
    }
    // next iter's barrier1 orders all buffer reuse
  }

  // =======================  FC tail (role 3, rank 0)  ========================
  if (role == 3 && rank == 0) {
    if (tid < 256) {                    // h2_0[255] -> sH[0]
      const u32x4* a = &g_q0s[S2 - 1][tid];
      u32x4 r = ld_sc_v4(a);
      while (r[2] != (unsigned)(S2 - 1)) r = ld_sc_v4(a);
      sH[0][swzH_pos(2 * tid)]     = r[0];
      sH[0][swzH_pos(2 * tid + 1)] = r[1];
    } else {                            // h2_1[255] -> sH[1]
      const u32x4* a = &g_q1s[S2 - 1][rid];
      u32x4 r = ld_sc_v4(a);
      while (r[2] != (unsigned)(S2 - 1)) r = ld_sc_v4(a);
      sH[1][swzH_pos(2 * rid)]     = r[0];
      sH[1][swzH_pos(2 * rid + 1)] = r[1];
    }
    __syncthreads();
    if (tid < 128) {
      const int l = tid >> 6, k = tid & 63;
      const unsigned* Hs = (const unsigned*)sH[l];
      const float* wrow = fc1W + (size_t)k * 1024;
      float acc = fc1b[k];
      for (int j2 = 0; j2 < 512; ++j2) {
        const unsigned hu = Hs[swzH_pos(j2)];
        acc += unpk(hu, 0) * wrow[2 * j2] + unpk(hu, 1) * wrow[2 * j2 + 1];
      }
      sY[tid] = sigf(acc);
    }
    __syncthreads();
    if (tid < 2) {
      const float* yv = sY + tid * 64;
      float acc = fc2b[0];
      for (int k2 = 0; k2 < 64; ++k2) acc += fc2W[k2] * yv[k2];
      out[tid] = sigf(acc);
    }
  }
}

extern "C" void kernel_launch(void* const* d_in, const int* in_sizes, int n_in,
                              void* d_out, int out_size, void* d_ws, size_t ws_size,
                              hipStream_t stream) {
  (void)in_sizes; (void)n_in; (void)out_size; (void)d_ws; (void)ws_size;
  const float* x      = (const float*)d_in[0];
  const float* g1_Wi0 = (const float*)d_in[1];
  const float* g1_Wh0 = (const float*)d_in[2];
  const float* g1_bi0 = (const float*)d_in[3];
  const float* g1_bh0 = (const float*)d_in[4];
  const float* g1_Wi1 = (const float*)d_in[5];
  const float* g1_Wh1 = (const float*)d_in[6];
  const float* g1_bi1 = (const float*)d_in[7];
  const float* g1_bh1 = (const float*)d_in[8];
  const float* g2_Wi0 = (const float*)d_in[9];
  const float* g2_Wh0 = (const float*)d_in[10];
  const float* g2_bi0 = (const float*)d_in[11];
  const float* g2_bh0 = (const float*)d_in[12];
  const float* g2_Wi1 = (const float*)d_in[13];
  const float* g2_Wh1 = (const float*)d_in[14];
  const float* g2_bi1 = (const float*)d_in[15];
  const float* g2_bh1 = (const float*)d_in[16];
  const float* fc1W   = (const float*)d_in[17];
  const float* fc1b   = (const float*)d_in[18];
  const float* fc2W   = (const float*)d_in[19];
  const float* fc2b   = (const float*)d_in[20];
  float* out = (float*)d_out;

  init_all<<<dim3(2048), dim3(256), 0, stream>>>();
  gru_all<<<dim3(256), dim3(512), 0, stream>>>(
      x, g1_Wi0, g1_Wh0, g1_bi0, g1_bh0, g1_Wi1, g1_Wh1, g1_bi1, g1_bh1,
      g2_Wi0, g2_Wh0, g2_bi0, g2_bh0, g2_Wi1, g2_Wh1, g2_bi1, g2_bh1,
      fc1W, fc1b, fc2W, fc2b, out);
}

// Round 13
// 25360.324 us; speedup vs baseline: 6.1865x; 1.0031x over previous
//
#include <hip/hip_runtime.h>

// ---------------------------------------------------------------------------
// GRUNet, round 13: r12 architecture + two de-serialization levers.
// r12 post-mortem: 4th consecutive sync-protocol null at 3.1us/step ->
// recurrence sync was never the pacer. Real pacers:
//  (1) stream batch-fetch = 4 SEQUENTIAL blocking sc1 RTTs (ld_sc_v4 embeds
//      vmcnt(0); k-loop serializes) ~1.5us/step amortized. FIX: stream waves
//      4..7 each own one batch step; 4 record-loads issued in ONE asm block,
//      single vmcnt(0) -> 1 parallel RTT per batch.
//  (2) weights spilled: need 192 VGPR/thread, allocator gave 128 (waves_per_eu
//      max ignored) -> ~100 regs re-read from scratch EVERY step on the dot
//      path. FIX: amdgpu_num_vgpr(256) (2 waves/SIMD x 256 = full file).
// Everything else (atomic64 recurrence, rings, tags, FC tail) = r12 verbatim.
// ---------------------------------------------------------------------------

typedef unsigned u32x4 __attribute__((ext_vector_type(4)));
typedef _Float16 h2_t  __attribute__((ext_vector_type(2)));

#define S1 8192
#define S2 256

__device__ u32x4 g_h0s[S1][256];   // history records {pair0,pair1,tag,0} (sc1)
__device__ u32x4 g_h1s[S1][256];
__device__ u32x4 g_q0s[S2][256];
__device__ u32x4 g_q1s[S2][256];
__device__ unsigned long long g_fast[4][2][512];  // {seq:32 | 2xf16:32}
__device__ int   g_claim[128];     // 4 roles x 32 slices

// ---- f16 pack/unpack ----
__device__ __forceinline__ unsigned pk(float a, float b) {
  unsigned short ua = __builtin_bit_cast(unsigned short, (_Float16)a);
  unsigned short ub = __builtin_bit_cast(unsigned short, (_Float16)b);
  return (unsigned)ua | ((unsigned)ub << 16);
}
__device__ __forceinline__ float unpk(unsigned u, int hi) {
  unsigned short us = (unsigned short)(hi ? (u >> 16) : (u & 0xffffu));
  return (float)__builtin_bit_cast(_Float16, us);
}

#if __has_builtin(__builtin_amdgcn_fdot2)
__device__ __forceinline__ float fdot2(unsigned a, unsigned b, float c) {
  return __builtin_amdgcn_fdot2(__builtin_bit_cast(h2_t, a),
                                __builtin_bit_cast(h2_t, b), c, false);
}
#else
__device__ __forceinline__ float fdot2(unsigned a, unsigned b, float c) {
  h2_t ha = __builtin_bit_cast(h2_t, a), hb = __builtin_bit_cast(h2_t, b);
  return c + (float)ha[0] * (float)hb[0] + (float)ha[1] * (float)hb[1];
}
#endif

// ---- sc1 (MALL-coherent) loads/stores ----
__device__ __forceinline__ u32x4 ld_sc_v4(const u32x4* p) {
  u32x4 v;
  asm volatile("global_load_dwordx4 %0, %1, off sc1\n\t"
               "s_waitcnt vmcnt(0)" : "=&v"(v) : "v"(p) : "memory");
  return v;
}
// 4 loads issued back-to-back, ONE wait: 1 RTT instead of 4.
__device__ __forceinline__ void ld_sc_4x4(const u32x4* p0, const u32x4* p1,
                                          const u32x4* p2, const u32x4* p3,
                                          u32x4& a, u32x4& b, u32x4& c, u32x4& d) {
  asm volatile("global_load_dwordx4 %0, %4, off sc1\n\t"
               "global_load_dwordx4 %1, %5, off sc1\n\t"
               "global_load_dwordx4 %2, %6, off sc1\n\t"
               "global_load_dwordx4 %3, %7, off sc1\n\t"
               "s_waitcnt vmcnt(0)"
               : "=&v"(a), "=&v"(b), "=&v"(c), "=&v"(d)
               : "v"(p0), "v"(p1), "v"(p2), "v"(p3) : "memory");
}
__device__ __forceinline__ void st_sc_v4(u32x4* p, u32x4 v) {
  asm volatile("global_store_dwordx4 %0, %1, off sc1" :: "v"(p), "v"(v) : "memory");
}

// ---- fast activations ----
__device__ __forceinline__ float rcpf(float x) {
#if __has_builtin(__builtin_amdgcn_rcpf)
  return __builtin_amdgcn_rcpf(x);
#else
  return 1.f / x;
#endif
}
__device__ __forceinline__ float sigf(float x) { return rcpf(1.f + __expf(-x)); }
__device__ __forceinline__ float tanh_f(float x) {
  x = fminf(fmaxf(x, -15.f), 15.f);
  const float e = __expf(2.f * x);
  return (e - 1.f) * rcpf(e + 1.f);
}

// ---- LDS swizzles ----
__device__ __forceinline__ int swzHc(int ch) { return ch ^ ((ch >> 3) & 7); }
__device__ __forceinline__ int swzH_pos(int i) { return (swzHc(i >> 2) << 2) | (i & 3); }
__device__ __forceinline__ int swzX_pos(int i) {
  int ch = i >> 2; ch ^= (ch >> 2) & 7; return (ch << 2) | (i & 3);
}

__global__ void init_all() {
  const long long NH = (long long)S1 * 256;
  const long long NQ = (long long)S2 * 256;
  const long long N  = 2 * NH + 2 * NQ;
  u32x4 ff = {0u, 0u, 0xFFFFFFFFu, 0u};
  const long long idx = (long long)blockIdx.x * blockDim.x + threadIdx.x;
  const long long str = (long long)gridDim.x * blockDim.x;
  for (long long k = idx; k < N; k += str) {
    u32x4* r;
    long long k2 = k;
    if (k2 < NH) r = &g_h0s[0][0] + k2;
    else {
      k2 -= NH;
      if (k2 < NH) r = &g_h1s[0][0] + k2;
      else {
        k2 -= NH;
        if (k2 < NQ) r = &g_q0s[0][0] + k2;
        else         r = &g_q1s[0][0] + (k2 - NQ);
      }
    }
    *r = ff;
  }
  for (long long k = idx; k < 4LL * 2 * 512; k += str)
    ((unsigned long long*)g_fast)[k] = 0xFFFFFFFF00000000ULL;
  if (blockIdx.x == 0 && threadIdx.x < 128) g_claim[threadIdx.x] = 0;
}

__device__ __forceinline__ const u32x4* in_addr(int role, int u, int r) {
  if (role == 1) return &g_h0s[u][r];
  if (role == 2) {
    const int ss = ((u >> 1) << 6) + 63;
    return (u & 1) ? &g_h1s[ss][r] : &g_h0s[ss][r];
  }
  return &g_q0s[u][r];
}
__device__ __forceinline__ unsigned in_want(int role, int u) {
  return (role == 2) ? (unsigned)(((u >> 1) << 6) + 63) : (unsigned)u;
}

#define MAC4(A, W4, H4)                                                       \
  A = fdot2((W4)[0], (H4)[0], A); A = fdot2((W4)[1], (H4)[1], A);             \
  A = fdot2((W4)[2], (H4)[2], A); A = fdot2((W4)[3], (H4)[3], A);

#define RED16(A)                                                              \
  A += __shfl_xor(A, 8, 16); A += __shfl_xor(A, 4, 16);                       \
  A += __shfl_xor(A, 2, 16); A += __shfl_xor(A, 1, 16);

// One wave fetches ALL 256 records of stream step u (4 recs/lane, 1 RTT),
// blocking-repoll until tags match, then stages into sIN[u&7].
#define STREAM_FETCH_WAVE(U, LN)                                              \
  {                                                                           \
    const unsigned w = in_want(role, (U));                                    \
    const u32x4* p0 = in_addr(role, (U), 4 * (LN) + 0);                       \
    const u32x4* p1 = in_addr(role, (U), 4 * (LN) + 1);                       \
    const u32x4* p2 = in_addr(role, (U), 4 * (LN) + 2);                       \
    const u32x4* p3 = in_addr(role, (U), 4 * (LN) + 3);                       \
    u32x4 r0, r1, r2, r3;                                                     \
    ld_sc_4x4(p0, p1, p2, p3, r0, r1, r2, r3);                                \
    while (r0[2] != w || r1[2] != w || r2[2] != w || r3[2] != w)              \
      ld_sc_4x4(p0, p1, p2, p3, r0, r1, r2, r3);                              \
    unsigned* dst = sIN[(U) & 7];                                             \
    const int b8 = 8 * (LN);                                                  \
    dst[swzH_pos(b8 + 0)] = r0[0]; dst[swzH_pos(b8 + 1)] = r0[1];             \
    dst[swzH_pos(b8 + 2)] = r1[0]; dst[swzH_pos(b8 + 3)] = r1[1];             \
    dst[swzH_pos(b8 + 4)] = r2[0]; dst[swzH_pos(b8 + 5)] = r2[1];             \
    dst[swzH_pos(b8 + 6)] = r3[0]; dst[swzH_pos(b8 + 7)] = r3[1];             \
  }

// One wave fetches the full 512-float x row of step u (8 floats/lane).
#define X_FETCH_WAVE(U, LN)                                                   \
  {                                                                           \
    const float4* xp = (const float4*)(x +                                    \
        (size_t)(((U) & 63) * 128 + ((U) >> 6)) * 512 + 8 * (LN));            \
    float4 a = xp[0], b = xp[1];                                              \
    unsigned* dst = sX[(U) & 7];                                              \
    const int b4 = 4 * (LN);                                                  \
    dst[swzX_pos(b4 + 0)] = pk(a.x, a.y);                                     \
    dst[swzX_pos(b4 + 1)] = pk(a.z, a.w);                                     \
    dst[swzX_pos(b4 + 2)] = pk(b.x, b.y);                                     \
    dst[swzX_pos(b4 + 3)] = pk(b.z, b.w);                                     \
  }

__global__
__attribute__((amdgpu_flat_work_group_size(512, 512), amdgpu_num_vgpr(256)))
void gru_all(const float* __restrict__ x,
             const float* __restrict__ g1_Wi0, const float* __restrict__ g1_Wh0,
             const float* __restrict__ g1_bi0, const float* __restrict__ g1_bh0,
             const float* __restrict__ g1_Wi1, const float* __restrict__ g1_Wh1,
             const float* __restrict__ g1_bi1, const float* __restrict__ g1_bh1,
             const float* __restrict__ g2_Wi0, const float* __restrict__ g2_Wh0,
             const float* __restrict__ g2_bi0, const float* __restrict__ g2_bh0,
             const float* __restrict__ g2_Wi1, const float* __restrict__ g2_Wh1,
             const float* __restrict__ g2_bi1, const float* __restrict__ g2_bh1,
             const float* __restrict__ fc1W, const float* __restrict__ fc1b,
             const float* __restrict__ fc2W, const float* __restrict__ fc2b,
             float* __restrict__ out)
{
  const int tid = threadIdx.x;
  const int G   = tid >> 4;            // 32 groups of 16 lanes
  const int q   = tid & 15;
  const int sw  = (tid >> 6) - 4;      // stream-wave id 0..3 (tid>=256)
  const int ln  = tid & 63;            // lane in wave
  const int rid = tid - 256;

  __shared__ __attribute__((aligned(16))) unsigned sH[2][512];   // own h[s-1]
  __shared__ __attribute__((aligned(16))) unsigned sIN[8][512];  // stream ring
  __shared__ __attribute__((aligned(16))) unsigned sX[8][256];   // x ring (role0)
  __shared__ float sD[96];             // Wh row dots
  __shared__ float sDI[96];            // Wi row dots
  __shared__ float sY[128];
  __shared__ int   sSlot;

  // ---- slot claim: prefer own-XCD role; bounded global fallback ----
  unsigned xcc;
  asm volatile("s_getreg_b32 %0, hwreg(HW_REG_XCC_ID)" : "=s"(xcc));
  xcc &= 7u;
  if (tid == 0) {
    int slot = -1;
    if (xcc < 4u) {
      for (int i = 0; i < 32 && slot < 0; ++i)
        if (atomicCAS(&g_claim[(int)xcc * 32 + i], 0, 1) == 0)
          slot = (int)xcc * 32 + i;
    }
    if (slot < 0) {
      for (int k = 0; k < 32; ++k) __builtin_amdgcn_s_sleep(64);  // ~60us
      for (int i = 0; i < 128 && slot < 0; ++i)
        if (atomicCAS(&g_claim[i], 0, 1) == 0) slot = i;
    }
    sSlot = slot;
  }
  __syncthreads();
  const int slot = sSlot;
  if (slot < 0) return;                // surplus WG
  const int role = slot >> 5;          // 0..3
  const int rank = slot & 31;          // h-slice [32*rank, +32)
  const int e0   = rank * 32;
  const int S    = (role <= 1) ? S1 : S2;

  const float* Wh  = (role == 0) ? g1_Wh0 : (role == 1) ? g1_Wh1
                   : (role == 2) ? g2_Wh0 : g2_Wh1;
  const float* Wi  = (role == 0) ? g1_Wi0 : (role == 1) ? g1_Wi1
                   : (role == 2) ? g2_Wi0 : g2_Wi1;
  const float* pbi = (role == 0) ? g1_bi0 : (role == 1) ? g1_bi1
                   : (role == 2) ? g2_bi0 : g2_bi1;
  const float* pbh = (role == 0) ? g1_bh0 : (role == 1) ? g1_bh1
                   : (role == 2) ? g2_bh0 : g2_bh1;
  u32x4 (*outA)[256] = (role == 0) ? g_h0s : (role == 1) ? g_h1s
                     : (role == 2) ? g_q0s : g_q1s;

  // ---- weights -> registers: group (G) owns 6 rows of ONE matrix ----
  u32x4 wv[6][8];
  {
    const bool isWh = (G < 16);
    const int  Gm   = isWh ? G : (G - 16);
    const float* M  = isWh ? Wh : Wi;
    const bool wide = isWh || (role != 0);
    #pragma unroll
    for (int j = 0; j < 6; ++j) {
      const int rr = Gm * 6 + j;
      const int R  = (rr >> 5) * 1024 + e0 + (rr & 31);
      if (wide) {
        const float4* rp = (const float4*)(M + (size_t)R * 1024 + 64 * q);
        #pragma unroll
        for (int c = 0; c < 8; ++c) {
          float4 a = rp[2 * c], b = rp[2 * c + 1];
          wv[j][c] = (u32x4){pk(a.x, a.y), pk(a.z, a.w), pk(b.x, b.y), pk(b.z, b.w)};
        }
      } else {
        const float4* rp = (const float4*)(M + (size_t)R * 512 + 32 * q);
        #pragma unroll
        for (int c = 0; c < 4; ++c) {
          float4 a = rp[2 * c], b = rp[2 * c + 1];
          wv[j][c] = (u32x4){pk(a.x, a.y), pk(a.z, a.w), pk(b.x, b.y), pk(b.z, b.w)};
        }
      }
    }
  }

  // ---- biases for combine lanes (tid<32 -> elem e0+tid) ----
  float bIr = 0, bIz = 0, bIn = 0, bHr = 0, bHz = 0, bHn = 0;
  if (tid < 32) {
    const int ge = e0 + tid;
    bIr = pbi[ge]; bIz = pbi[1024 + ge]; bIn = pbi[2048 + ge];
    bHr = pbh[ge]; bHz = pbh[1024 + ge]; bHn = pbh[2048 + ge];
  }

  // ---- stream prologue: wave 4+k fetches step k (parallel across waves) ----
  if (tid >= 256) {
    const int u = sw;                  // 0..3 (< S always)
    if (role == 0) { X_FETCH_WAVE(u, ln); }
    else           { STREAM_FETCH_WAVE(u, ln); }
  }
  __syncthreads();

  // =======================  serial scan  =======================
  for (int s = 0; s < S; ++s) {
    const int par = s & 1;

    // ---- stream batch-fetch: wave 4+k owns step s+4+k (1 parallel RTT) ----
    if (tid >= 256 && (s & 3) == 0) {
      const int u = s + 4 + sw;
      if (u < S) {
        if (role == 0) { X_FETCH_WAVE(u, ln); }
        else           { STREAM_FETCH_WAVE(u, ln); }
      }
    }

    // ---- own recurrence poll: atomic64 records (data+seq in one op) ----
    if (tid < 256) {
      unsigned d0 = 0, d1 = 0;
      if (s > 0) {
        const unsigned w = (unsigned)(s - 1);
        unsigned long long* f0 = &g_fast[role][(s - 1) & 1][2 * tid];
        unsigned long long* f1 = f0 + 1;
        unsigned long long v0 = atomicAdd(f0, 0ull);
        unsigned long long v1 = atomicAdd(f1, 0ull);
        bool o0 = ((unsigned)(v0 >> 32) == w), o1 = ((unsigned)(v1 >> 32) == w);
        while (!(o0 && o1)) {
          if (!o0) v0 = atomicAdd(f0, 0ull);
          if (!o1) v1 = atomicAdd(f1, 0ull);
          o0 = ((unsigned)(v0 >> 32) == w); o1 = ((unsigned)(v1 >> 32) == w);
        }
        d0 = (unsigned)v0; d1 = (unsigned)v1;
      }
      sH[par][swzH_pos(2 * tid)]     = d0;
      sH[par][swzH_pos(2 * tid + 1)] = d1;
    }
    __syncthreads();                                   // barrier 1

    // ---- row dots (register weights x LDS operand) ----
    float a0 = 0, a1 = 0, a2 = 0, a3 = 0, a4 = 0, a5 = 0;
    if (G < 16) {                                      // Wh groups: h[s-1]
      const u32x4* HV = (const u32x4*)sH[par];
      #pragma unroll
      for (int c = 0; c < 8; ++c) {
        const u32x4 h4 = HV[8 * q + (c ^ (q & 7))];
        MAC4(a0, wv[0][c], h4); MAC4(a1, wv[1][c], h4); MAC4(a2, wv[2][c], h4);
        MAC4(a3, wv[3][c], h4); MAC4(a4, wv[4][c], h4); MAC4(a5, wv[5][c], h4);
      }
    } else if (role != 0) {                            // Wi groups: stream
      const u32x4* IV = (const u32x4*)sIN[s & 7];
      #pragma unroll
      for (int c = 0; c < 8; ++c) {
        const u32x4 h4 = IV[8 * q + (c ^ (q & 7))];
        MAC4(a0, wv[0][c], h4); MAC4(a1, wv[1][c], h4); MAC4(a2, wv[2][c], h4);
        MAC4(a3, wv[3][c], h4); MAC4(a4, wv[4][c], h4); MAC4(a5, wv[5][c], h4);
      }
    } else {                                           // role0 Wi: x (512 col)
      const u32x4* XV = (const u32x4*)sX[s & 7];
      #pragma unroll
      for (int c = 0; c < 4; ++c) {
        const int ch = 4 * q + c;
        const u32x4 h4 = XV[ch ^ ((ch >> 2) & 7)];
        MAC4(a0, wv[0][c], h4); MAC4(a1, wv[1][c], h4); MAC4(a2, wv[2][c], h4);
        MAC4(a3, wv[3][c], h4); MAC4(a4, wv[4][c], h4); MAC4(a5, wv[5][c], h4);
      }
    }
    RED16(a0); RED16(a1); RED16(a2); RED16(a3); RED16(a4); RED16(a5);
    if (q < 6) {
      const float v = (q == 0) ? a0 : (q == 1) ? a1 : (q == 2) ? a2
                    : (q == 3) ? a3 : (q == 4) ? a4 : a5;
      if (G < 16) sD[G * 6 + q] = v;
      else        sDI[(G - 16) * 6 + q] = v;
    }
    __syncthreads();                                   // barrier 2

    // ---- gate combine + publish (lanes 0..31 of wave 0) ----
    if (tid < 32) {
      const float rg = sigf(sDI[tid] + bIr + sD[tid] + bHr);
      const float zg = sigf(sDI[32 + tid] + bIz + sD[32 + tid] + bHz);
      const float ng = tanh_f(sDI[64 + tid] + bIn + rg * (sD[64 + tid] + bHn));
      const int ge = e0 + tid;
      const float hp = unpk(sH[par][swzH_pos(ge >> 1)], ge & 1);
      const float hn = (1.f - zg) * ng + zg * hp;
      // shuffles with all 32 source lanes active (r8-proven); stores guarded.
      const int i2 = (tid & 15) * 2;
      const float p0 = __shfl(hn, i2), p1 = __shfl(hn, i2 + 1);
      const int b4 = (tid & 7) * 4;
      const float v0 = __shfl(hn, b4),     v1 = __shfl(hn, b4 + 1);
      const float v2 = __shfl(hn, b4 + 2), v3 = __shfl(hn, b4 + 3);
      if (tid < 16) {                                  // fast path FIRST
        unsigned long long val =
            ((unsigned long long)(unsigned)s << 32) | (unsigned long long)pk(p0, p1);
        atomicExch(&g_fast[role][s & 1][rank * 16 + tid], val);
      }
      if (tid < 8) {                                   // history/stream (sc1)
        u32x4 rec = {pk(v0, v1), pk(v2, v3), (unsigned)s, 0u};
        st_sc_v4(&outA[s][rank * 8 + tid], rec);
      }
    }
    // next iter's barrier1 orders all buffer reuse
  }

  // =======================  FC tail (role 3, rank 0)  ========================
  if (role == 3 && rank == 0) {
    if (tid < 256) {                    // h2_0[255] -> sH[0]
      const u32x4* a = &g_q0s[S2 - 1][tid];
      u32x4 r = ld_sc_v4(a);
      while (r[2] != (unsigned)(S2 - 1)) r = ld_sc_v4(a);
      sH[0][swzH_pos(2 * tid)]     = r[0];
      sH[0][swzH_pos(2 * tid + 1)] = r[1];
    } else {                            // h2_1[255] -> sH[1]
      const u32x4* a = &g_q1s[S2 - 1][rid];
      u32x4 r = ld_sc_v4(a);
      while (r[2] != (unsigned)(S2 - 1)) r = ld_sc_v4(a);
      sH[1][swzH_pos(2 * rid)]     = r[0];
      sH[1][swzH_pos(2 * rid + 1)] = r[1];
    }
    __syncthreads();
    if (tid < 128) {
      const int l = tid >> 6, k = tid & 63;
      const unsigned* Hs = (const unsigned*)sH[l];
      const float* wrow = fc1W + (size_t)k * 1024;
      float acc = fc1b[k];
      for (int j2 = 0; j2 < 512; ++j2) {
        const unsigned hu = Hs[swzH_pos(j2)];
        acc += unpk(hu, 0) * wrow[2 * j2] + unpk(hu, 1) * wrow[2 * j2 + 1];
      }
      sY[tid] = sigf(acc);
    }
    __syncthreads();
    if (tid < 2) {
      const float* yv = sY + tid * 64;
      float acc = fc2b[0];
      for (int k2 = 0; k2 < 64; ++k2) acc += fc2W[k2] * yv[k2];
      out[tid] = sigf(acc);
    }
  }
}

extern "C" void kernel_launch(void* const* d_in, const int* in_sizes, int n_in,
                              void* d_out, int out_size, void* d_ws, size_t ws_size,
                              hipStream_t stream) {
  (void)in_sizes; (void)n_in; (void)out_size; (void)d_ws; (void)ws_size;
  const float* x      = (const float*)d_in[0];
  const float* g1_Wi0 = (const float*)d_in[1];
  const float* g1_Wh0 = (const float*)d_in[2];
  const float* g1_bi0 = (const float*)d_in[3];
  const float* g1_bh0 = (const float*)d_in[4];
  const float* g1_Wi1 = (const float*)d_in[5];
  const float* g1_Wh1 = (const float*)d_in[6];
  const float* g1_bi1 = (const float*)d_in[7];
  const float* g1_bh1 = (const float*)d_in[8];
  const float* g2_Wi0 = (const float*)d_in[9];
  const float* g2_Wh0 = (const float*)d_in[10];
  const float* g2_bi0 = (const float*)d_in[11];
  const float* g2_bh0 = (const float*)d_in[12];
  const float* g2_Wi1 = (const float*)d_in[13];
  const float* g2_Wh1 = (const float*)d_in[14];
  const float* g2_bi1 = (const float*)d_in[15];
  const float* g2_bh1 = (const float*)d_in[16];
  const float* fc1W   = (const float*)d_in[17];
  const float* fc1b   = (const float*)d_in[18];
  const float* fc2W   = (const float*)d_in[19];
  const float* fc2b   = (const float*)d_in[20];
  float* out = (float*)d_out;

  init_all<<<dim3(2048), dim3(256), 0, stream>>>();
  gru_all<<<dim3(256), dim3(512), 0, stream>>>(
      x, g1_Wi0, g1_Wh0, g1_bi0, g1_bh0, g1_Wi1, g1_Wh1, g1_bi1, g1_bh1,
      g2_Wi0, g2_Wh0, g2_bi0, g2_bh0, g2_Wi1, g2_Wh1, g2_bi1, g2_bh1,
      fc1W, fc1b, fc2W, fc2b, out);
}